// Round 3
// baseline (127.269 us; speedup 1.0000x reference)
//
#include <hip/hip_runtime.h>
#include <stdint.h>

#define H_HEADS 8
#define DDIM 64
#define NNODES 8192
#define BB 2
#define FIN 512
#define FOUT 512
#define EDGES 65536
#define CAP 32   // per-node edge bucket capacity (Poisson λ=8; P(deg>=32)~1e-11)

typedef unsigned short u16;
typedef unsigned int u32;
typedef __bf16 bf16x8 __attribute__((ext_vector_type(8)));
typedef float f32x4 __attribute__((ext_vector_type(4)));

__device__ __forceinline__ u16 f2bf(float f) {
    u32 u = __float_as_uint(f);
    return (u16)((u + 0x7FFFu + ((u >> 16) & 1u)) >> 16);
}
__device__ __forceinline__ float bf2f(u32 s) {
    return __uint_as_float(s << 16);
}
__device__ __forceinline__ uint4 pack8(float4 a, float4 b) {
    return make_uint4(f2bf(a.x) | ((u32)f2bf(a.y) << 16),
                      f2bf(a.z) | ((u32)f2bf(a.w) << 16),
                      f2bf(b.x) | ((u32)f2bf(b.y) << 16),
                      f2bf(b.z) | ((u32)f2bf(b.w) << 16));
}

// ---------------- prep: cast W -> bf16  +  edge bucket build ----------------
// (X is NOT cast anymore: gemm stages fp32 X via global_load_lds and converts
// in-register — kills the 96 MB Xb round-trip.)
#define NEB 64                               // 64 blocks * 256 thr * 4 edges
#define NWB (FOUT * FIN / 8 / 256)           // 128 blocks
__global__ __launch_bounds__(256) void prep_kernel(
    const float* __restrict__ W, const int* __restrict__ src,
    const int* __restrict__ dst, u16* __restrict__ Wb,
    int* __restrict__ cursor, int* __restrict__ le_pack,
    int* __restrict__ csr_dst) {
    int blk = blockIdx.x;
    if (blk < NEB) {
        int t = blk * 256 + threadIdx.x;  // 0..16383
#pragma unroll
        for (int k = 0; k < 4; k++) {
            int e = t * 4 + k;
            int s = src[e], d = dst[e];
            int slot = atomicAdd(&cursor[s], 1);
            if (slot < CAP) csr_dst[(size_t)s * CAP + slot] = d;
            // packed argmax-by-e; all packs >= 0 so memset-0 init is safe
            // (pk only consumed when deg>0)
            atomicMax(&le_pack[s], (e << 13) | d);
        }
    } else {
        int i = (blk - NEB) * 256 + threadIdx.x;
        const float4* p = (const float4*)W;
        float4 v0 = p[(size_t)i * 2], v1 = p[(size_t)i * 2 + 1];
        ((uint4*)Wb)[i] = pack8(v0, v1);
    }
}

// ---------------- bf16 MFMA GEMM, A = fp32 X staged via GLDS ----------------
// 3 LDS buffers; counted s_waitcnt vmcnt(6) (= next tile's 6 loads in
// flight); ONE barrier per K-step; STAGE(t+2) issued before compute.
// A-tile is f32 [128][32] with byte-XOR swizzle ((row&7)<<4) applied on the
// GLOBAL source side (GLDS dest must stay linear) and on the LDS read side.
#define GLDS(g, l)                                                              \
    __builtin_amdgcn_global_load_lds(                                           \
        (const __attribute__((address_space(1))) u32*)(g),                      \
        (__attribute__((address_space(3))) u32*)(l), 16, 0, 0)

__global__ __launch_bounds__(256) void gemm_mfma(const float* __restrict__ X,
                                                 const u16* __restrict__ Bm,
                                                 const float* __restrict__ a,
                                                 u16* __restrict__ C,
                                                 float* __restrict__ s1,
                                                 float* __restrict__ s2) {
    __shared__ __align__(16) float AsF[3][128 * 32];
    __shared__ __align__(16) u16 Bs[3][128 * 32];
    int tid = threadIdx.x;
    // XCD swizzle: the 4 n-blocks sharing one A-tile get blockIdx values
    // {b, b+8, b+16, b+24} -> same XCD (blk%8) -> A re-reads hit that XCD's L2.
    int gb = blockIdx.x;
    int m_idx = (gb & 7) | ((gb >> 5) << 3);   // 0..127
    int n_idx = (gb >> 3) & 3;                 // 0..3
    int m0 = m_idx * 128, n0 = n_idx * 128;
    int lane = tid & 63, wv = tid >> 6;
    int wr = (wv >> 1) * 64, wc = (wv & 1) * 64;
    int l15 = lane & 15, quad = lane >> 4;
    f32x4 acc[4][4] = {};

    // A staging map (f32): thread covers 4 f32 = 16 B. Linear LDS dest byte
    // = call*4096 + tid*16 -> (row = call*32 + tid>>3, chunk = tid&7).
    // Stored chunk holds global k-chunk (chunk ^ (row&7)) -> pre-swizzle src.
    int srA = tid >> 3;                          // 0..31
    int scA = ((tid & 7) ^ (srA & 7)) * 4;       // swizzled f32 col offset
    const float* AgSw = X + (size_t)(m0 + srA) * FIN + scA;

    // B staging (bf16, linear as before)
    int srB = tid >> 2;                          // 0..63
    int scB = (tid & 3) * 8;                     // k-offset 0/8/16/24
    const u16* Bg = Bm + (size_t)(n0 + srB) * FIN + scB;

#define STAGE(c, kk)                                                            \
    do {                                                                        \
        float* Al_ = AsF[c] + tid * 4;                                          \
        u16* Bl_ = Bs[c] + tid * 8;                                             \
        GLDS(AgSw + (kk), Al_);                                                 \
        GLDS(AgSw + (kk) + (size_t)32 * FIN, Al_ + 32 * 32);                    \
        GLDS(AgSw + (kk) + (size_t)64 * FIN, Al_ + 64 * 32);                    \
        GLDS(AgSw + (kk) + (size_t)96 * FIN, Al_ + 96 * 32);                    \
        GLDS(Bg + (kk), Bl_);                                                   \
        GLDS(Bg + (kk) + (size_t)64 * FIN, Bl_ + 64 * 32);                      \
    } while (0)

#define COMPUTE(c)                                                              \
    do {                                                                        \
        bf16x8 af[4], bfr[4];                                                   \
        _Pragma("unroll") for (int i = 0; i < 4; i++) {                         \
            int r_ = wr + i * 16 + l15;                                         \
            const float* bp_ = AsF[c] + r_ * 32;                                \
            int sx_ = r_ & 7;                                                   \
            f32x4 v0_ = *(const f32x4*)(bp_ + (((quad * 2 + 0) ^ sx_) << 2));   \
            f32x4 v1_ = *(const f32x4*)(bp_ + (((quad * 2 + 1) ^ sx_) << 2));   \
            bf16x8 t_;                                                          \
            t_[0] = (__bf16)v0_[0]; t_[1] = (__bf16)v0_[1];                     \
            t_[2] = (__bf16)v0_[2]; t_[3] = (__bf16)v0_[3];                     \
            t_[4] = (__bf16)v1_[0]; t_[5] = (__bf16)v1_[1];                     \
            t_[6] = (__bf16)v1_[2]; t_[7] = (__bf16)v1_[3];                     \
            af[i] = t_;                                                         \
        }                                                                       \
        _Pragma("unroll") for (int j = 0; j < 4; j++) bfr[j] =                  \
            *(const bf16x8*)(Bs[c] + (wc + j * 16 + l15) * 32 + quad * 8);      \
        _Pragma("unroll") for (int i = 0; i < 4; i++)                           \
            _Pragma("unroll") for (int j = 0; j < 4; j++) acc[i][j] =           \
                __builtin_amdgcn_mfma_f32_16x16x32_bf16(af[i], bfr[j],          \
                                                        acc[i][j], 0, 0, 0);    \
    } while (0)

    STAGE(0, 0);
    STAGE(1, 32);
    int c0 = 0, c2 = 2;
#pragma unroll 1
    for (int t = 0; t < 14; ++t) {
        asm volatile("s_waitcnt vmcnt(6)" ::: "memory");
        __builtin_amdgcn_s_barrier();
        __builtin_amdgcn_sched_barrier(0);
        STAGE(c2, (t + 2) * 32);
        COMPUTE(c0);
        c0 = (c0 == 2) ? 0 : c0 + 1;
        c2 = (c2 == 2) ? 0 : c2 + 1;
    }
    // t = 14: reads buf 2 (tile15's 6 loads still in flight)
    asm volatile("s_waitcnt vmcnt(6)" ::: "memory");
    __builtin_amdgcn_s_barrier();
    __builtin_amdgcn_sched_barrier(0);
    COMPUTE(2);
    // t = 15: reads buf 0
    asm volatile("s_waitcnt vmcnt(0)" ::: "memory");
    __builtin_amdgcn_s_barrier();
    __builtin_amdgcn_sched_barrier(0);
    COMPUTE(0);

    // h store (bf16)
#pragma unroll
    for (int i = 0; i < 4; i++) {
        int row_base = m0 + wr + i * 16 + quad * 4;
#pragma unroll
        for (int j = 0; j < 4; j++) {
            int col = n0 + wc + j * 16 + l15;
#pragma unroll
            for (int r = 0; r < 4; r++)
                C[(size_t)(row_base + r) * FOUT + col] = f2bf(acc[i][j][r]);
        }
    }

    // fused score: this wave's 64 cols == exactly one head
    // (a-vector loads deferred here so the K-loop's vmcnt counts only GLDS)
    float a1v[4], a2v[4];
#pragma unroll
    for (int j = 0; j < 4; j++) {
        a1v[j] = a[j * 16 + l15];
        a2v[j] = a[DDIM + j * 16 + l15];
    }
    int head = n_idx * 2 + (wv & 1);
#pragma unroll
    for (int i = 0; i < 4; i++) {
#pragma unroll
        for (int r = 0; r < 4; r++) {
            float p1 = 0.f, p2 = 0.f;
#pragma unroll
            for (int j = 0; j < 4; j++) {
                p1 += a1v[j] * acc[i][j][r];
                p2 += a2v[j] * acc[i][j][r];
            }
#pragma unroll
            for (int m = 1; m <= 8; m <<= 1) {
                p1 += __shfl_xor(p1, m);
                p2 += __shfl_xor(p2, m);
            }
            if (l15 == 0) {
                int row = m0 + wr + i * 16 + quad * 4 + r;
                s1[row * H_HEADS + head] = p1;
                s2[row * H_HEADS + head] = p2;
            }
        }
    }
}

// ---------------- aggregate + fused softmax weights ------------------------
// 2 nodes/block; wave = (node, batch); lane: head=l>>3, d=(l&7)*8..+8.
// Predicated groups-of-4 (pad row 0 is universally hot in L2/L3 — cheaper
// than a serial dependent-load tail).
__global__ __launch_bounds__(256) void aggregate(const u16* __restrict__ h,
                                                 const float* __restrict__ s1,
                                                 const float* __restrict__ s2,
                                                 const int* __restrict__ cursor,
                                                 const int* __restrict__ le_pack,
                                                 const int* __restrict__ csr_dst,
                                                 float* __restrict__ out, int N) {
    int n = blockIdx.x * 2 + (threadIdx.x >> 7);
    int b = (threadIdx.x >> 6) & 1;
    int lane = threadIdx.x & 63;
    int head = lane >> 3;

    int deg = cursor[n];
    deg = deg < CAP ? deg : CAP;
    int pk = le_pack[n];

    // cooperative index fetch: lanes 0..31 hold this node's bucket
    const int* cp = csr_dst + (size_t)n * CAP;
    int myidx = (lane < CAP) ? cp[lane] : 0;

    float wgt = 0.f;
    if (deg > 0) {
        int dl = pk & 8191;
        float sc0 = s1[(0 * N + n) * H_HEADS + head] +
                    s2[((size_t)0 * N + dl) * H_HEADS + head];
        float sc1 = s1[((size_t)1 * N + n) * H_HEADS + head] +
                    s2[((size_t)1 * N + dl) * H_HEADS + head];
        sc0 = sc0 >= 0.f ? sc0 : 0.2f * sc0;
        sc1 = sc1 >= 0.f ? sc1 : 0.2f * sc1;
        float m = fmaxf(sc0, sc1);
        float e0 = __expf(sc0 - m), e1 = __expf(sc1 - m);
        wgt = (b == 0 ? e0 : e1) / (e0 + e1);
    }

    float acc[8] = {};
    const u16* hb = h + (size_t)b * N * FOUT + lane * 8;
    for (int j0 = 0; j0 < deg; j0 += 4) {
#pragma unroll
        for (int k = 0; k < 4; k++) {
            int j = j0 + k;
            float f = (j < deg) ? 1.0f : 0.0f;     // wave-uniform
            int dn = (j < deg) ? __shfl(myidx, j) : 0;
            uint4 v = *(const uint4*)(hb + (size_t)dn * FOUT);
            acc[0] = fmaf(f, bf2f(v.x & 0xffffu), acc[0]);
            acc[1] = fmaf(f, bf2f(v.x >> 16), acc[1]);
            acc[2] = fmaf(f, bf2f(v.y & 0xffffu), acc[2]);
            acc[3] = fmaf(f, bf2f(v.y >> 16), acc[3]);
            acc[4] = fmaf(f, bf2f(v.z & 0xffffu), acc[4]);
            acc[5] = fmaf(f, bf2f(v.z >> 16), acc[5]);
            acc[6] = fmaf(f, bf2f(v.w & 0xffffu), acc[6]);
            acc[7] = fmaf(f, bf2f(v.w >> 16), acc[7]);
        }
    }

    float val[8];
#pragma unroll
    for (int k = 0; k < 8; k++) val[k] = acc[k] * wgt;
#pragma unroll
    for (int m = 8; m <= 32; m <<= 1)
#pragma unroll
        for (int k = 0; k < 8; k++) val[k] += __shfl_xor(val[k], m);
    if (lane < 8) {
        float* op = out + ((size_t)b * N + n) * DDIM + lane * 8;
        const float inv = 1.0f / H_HEADS;
        *(float4*)op = make_float4(val[0] * inv, val[1] * inv, val[2] * inv,
                                   val[3] * inv);
        *(float4*)(op + 4) = make_float4(val[4] * inv, val[5] * inv,
                                         val[6] * inv, val[7] * inv);
    }
}

// ---------------------------------------------------------------------------
extern "C" void kernel_launch(void* const* d_in, const int* in_sizes, int n_in,
                              void* d_out, int out_size, void* d_ws,
                              size_t ws_size, hipStream_t stream) {
    const float* x = (const float*)d_in[0];
    const int* edges = (const int*)d_in[1];
    const float* W = (const float*)d_in[2];
    const float* a = (const float*)d_in[3];
    float* out = (float*)d_out;

    const int* src = edges;
    const int* dst = edges + EDGES;

    char* p = (char*)d_ws;
    auto carve = [&](size_t bytes) {
        char* r = p;
        p += (bytes + 255) & ~(size_t)255;
        return r;
    };
    u16* Wb = (u16*)carve((size_t)FOUT * FIN * 2);
    u16* h = (u16*)carve((size_t)BB * NNODES * FOUT * 2);
    float* s1 = (float*)carve((size_t)BB * NNODES * H_HEADS * 4);
    float* s2 = (float*)carve((size_t)BB * NNODES * H_HEADS * 4);
    int* cursor = (int*)carve(NNODES * 4);       // adjacent: one memset
    int* le_pack = (int*)carve(NNODES * 4);
    int* csr_dst = (int*)carve((size_t)NNODES * CAP * 4);

    const int M = BB * NNODES;

    // zero cursor + le_pack (adjacent 64 KB); all le packs >= 0 and pk is
    // only consumed when deg>0, so 0-init is safe.
    hipMemsetAsync(cursor, 0, 2 * NNODES * 4, stream);
    prep_kernel<<<NEB + NWB, 256, 0, stream>>>(W, src, dst, Wb, cursor,
                                               le_pack, csr_dst);
    gemm_mfma<<<(M / 128) * (FOUT / 128), 256, 0, stream>>>(x, Wb, a, h, s1,
                                                            s2);
    aggregate<<<NNODES / 2, 256, 0, stream>>>(h, s1, s2, cursor, le_pack,
                                              csr_dst, out, NNODES);
}

// Round 4
// 124.423 us; speedup vs baseline: 1.0229x; 1.0229x over previous
//
#include <hip/hip_runtime.h>
#include <stdint.h>

#define H_HEADS 8
#define DDIM 64
#define NNODES 8192
#define BB 2
#define FIN 512
#define FOUT 512
#define EDGES 65536
#define CAP 32   // per-node edge bucket capacity (Poisson λ=8; P(deg>=32)~1e-11)

typedef unsigned short u16;
typedef unsigned int u32;
typedef __bf16 bf16x8 __attribute__((ext_vector_type(8)));
typedef float f32x4 __attribute__((ext_vector_type(4)));

__device__ __forceinline__ u16 f2bf(float f) {
    u32 u = __float_as_uint(f);
    return (u16)((u + 0x7FFFu + ((u >> 16) & 1u)) >> 16);
}
__device__ __forceinline__ float bf2f(u32 s) {
    return __uint_as_float(s << 16);
}
__device__ __forceinline__ uint4 pack8(float4 a, float4 b) {
    return make_uint4(f2bf(a.x) | ((u32)f2bf(a.y) << 16),
                      f2bf(a.z) | ((u32)f2bf(a.w) << 16),
                      f2bf(b.x) | ((u32)f2bf(b.y) << 16),
                      f2bf(b.z) | ((u32)f2bf(b.w) << 16));
}

// ---------------- K1: zero cursor+le_pack + cast W -> bf16 ------------------
// 128 blocks * 256 thr = 32768 threads = exactly the W-cast width.
// cursor and le_pack are carve-adjacent (8192+8192 ints = 4096 int4).
__global__ __launch_bounds__(256) void init_kernel(const float* __restrict__ W,
                                                   u16* __restrict__ Wb,
                                                   int* __restrict__ zero_base) {
    int tg = blockIdx.x * 256 + threadIdx.x;   // 0..32767
    if (tg < 4096) ((int4*)zero_base)[tg] = make_int4(0, 0, 0, 0);
    const float4* p = (const float4*)W;
    float4 v0 = p[(size_t)tg * 2], v1 = p[(size_t)tg * 2 + 1];
    ((uint4*)Wb)[tg] = pack8(v0, v1);
}

// ---------------- K2: edge bucket build + bf16 MFMA GEMM --------------------
// First 65536 threads each process one edge (consumed only by the aggregate
// dispatch -> stream order covers visibility; atomics' latency hides under
// the first tile staging). Then all threads run the round-0 gemm (best
// measured): A reg-staged fp32->bf16, B via global_load_lds.
#define GLDS(g, l)                                                              \
    __builtin_amdgcn_global_load_lds(                                           \
        (const __attribute__((address_space(1))) u32*)(g),                      \
        (__attribute__((address_space(3))) u32*)(l), 16, 0, 0)

__global__ __launch_bounds__(256) void gemm_edges(
    const float* __restrict__ X, const u16* __restrict__ Bm,
    const float* __restrict__ a, const int* __restrict__ src,
    const int* __restrict__ dst, u16* __restrict__ C,
    float* __restrict__ s1, float* __restrict__ s2, int* __restrict__ cursor,
    int* __restrict__ le_pack, int* __restrict__ csr_dst) {
    int tid = threadIdx.x;
    int tg = blockIdx.x * 256 + tid;
    if (tg < EDGES) {
        int s = src[tg], d = dst[tg];
        int slot = atomicAdd(&cursor[s], 1);
        if (slot < CAP) csr_dst[(size_t)s * CAP + slot] = d;
        // packed argmax-by-e; all packs >= 0 so zero-init is safe
        // (pk only consumed when deg>0)
        atomicMax(&le_pack[s], (tg << 13) | d);
    }

    __shared__ u16 As[128 * 32];
    __shared__ u16 Bs[128 * 32];
    // XCD swizzle: the 4 n-blocks sharing one A-tile get blockIdx values
    // {b, b+8, b+16, b+24} -> same XCD (blk%8) -> A re-reads hit that XCD's L2.
    int gb = blockIdx.x;
    int m_idx = (gb & 7) | ((gb >> 5) << 3);   // 0..127
    int n_idx = (gb >> 3) & 3;                 // 0..3
    int m0 = m_idx * 128, n0 = n_idx * 128;
    int lane = tid & 63, wv = tid >> 6;
    int wr = (wv >> 1) * 64, wc = (wv & 1) * 64;
    int l15 = lane & 15, quad = lane >> 4;
    f32x4 acc[4][4] = {};

    float a1v[4], a2v[4];
#pragma unroll
    for (int j = 0; j < 4; j++) {
        a1v[j] = a[j * 16 + l15];
        a2v[j] = a[DDIM + j * 16 + l15];
    }

    int srow = tid >> 2;         // 0..63
    int scol = (tid & 3) * 8;    // k-offset 0/8/16/24
    const float* Ag = X + (size_t)(m0 + srow) * FIN + scol;
    const u16* Bg = Bm + (size_t)(n0 + srow) * FIN + scol;
    u16* Al = As + tid * 8;
    u16* Bl = Bs + tid * 8;

    for (int k0 = 0; k0 < FIN; k0 += 32) {
        __syncthreads();
        GLDS(Bg + k0, Bl);
        GLDS(Bg + k0 + (size_t)64 * FIN, Bl + 64 * 32);
        float4 fa0 = *(const float4*)(Ag + k0);
        float4 fa1 = *(const float4*)(Ag + k0 + 4);
        float4 fb0 = *(const float4*)(Ag + k0 + (size_t)64 * FIN);
        float4 fb1 = *(const float4*)(Ag + k0 + (size_t)64 * FIN + 4);
        *(uint4*)Al = pack8(fa0, fa1);
        *(uint4*)(Al + 64 * 32) = pack8(fb0, fb1);
        __syncthreads();
        bf16x8 af[4], bfr[4];
#pragma unroll
        for (int i = 0; i < 4; i++)
            af[i] = *(const bf16x8*)(As + (wr + i * 16 + l15) * 32 + quad * 8);
#pragma unroll
        for (int j = 0; j < 4; j++)
            bfr[j] = *(const bf16x8*)(Bs + (wc + j * 16 + l15) * 32 + quad * 8);
#pragma unroll
        for (int i = 0; i < 4; i++)
#pragma unroll
            for (int j = 0; j < 4; j++)
                acc[i][j] = __builtin_amdgcn_mfma_f32_16x16x32_bf16(
                    af[i], bfr[j], acc[i][j], 0, 0, 0);
    }

    // h store (bf16)
#pragma unroll
    for (int i = 0; i < 4; i++) {
        int row_base = m0 + wr + i * 16 + quad * 4;
#pragma unroll
        for (int j = 0; j < 4; j++) {
            int col = n0 + wc + j * 16 + l15;
#pragma unroll
            for (int r = 0; r < 4; r++)
                C[(size_t)(row_base + r) * FOUT + col] = f2bf(acc[i][j][r]);
        }
    }

    // fused score: this wave's 64 cols == exactly one head
    int head = n_idx * 2 + (wv & 1);
#pragma unroll
    for (int i = 0; i < 4; i++) {
#pragma unroll
        for (int r = 0; r < 4; r++) {
            float p1 = 0.f, p2 = 0.f;
#pragma unroll
            for (int j = 0; j < 4; j++) {
                p1 += a1v[j] * acc[i][j][r];
                p2 += a2v[j] * acc[i][j][r];
            }
#pragma unroll
            for (int m = 1; m <= 8; m <<= 1) {
                p1 += __shfl_xor(p1, m);
                p2 += __shfl_xor(p2, m);
            }
            if (l15 == 0) {
                int row = m0 + wr + i * 16 + quad * 4 + r;
                s1[row * H_HEADS + head] = p1;
                s2[row * H_HEADS + head] = p2;
            }
        }
    }
}

// ---------------- aggregate + fused softmax weights ------------------------
// 2 nodes/block; wave = (node, batch); lane: head=l>>3, d=(l&7)*8..+8.
__global__ __launch_bounds__(256) void aggregate(const u16* __restrict__ h,
                                                 const float* __restrict__ s1,
                                                 const float* __restrict__ s2,
                                                 const int* __restrict__ cursor,
                                                 const int* __restrict__ le_pack,
                                                 const int* __restrict__ csr_dst,
                                                 float* __restrict__ out, int N) {
    int n = blockIdx.x * 2 + (threadIdx.x >> 7);
    int b = (threadIdx.x >> 6) & 1;
    int lane = threadIdx.x & 63;
    int head = lane >> 3;

    int deg = cursor[n];
    deg = deg < CAP ? deg : CAP;
    int pk = le_pack[n];

    // cooperative index fetch: lanes 0..31 hold this node's bucket
    const int* cp = csr_dst + (size_t)n * CAP;
    int myidx = (lane < CAP) ? cp[lane] : 0;

    float wgt = 0.f;
    if (deg > 0) {
        int dl = pk & 8191;
        float sc0 = s1[(0 * N + n) * H_HEADS + head] +
                    s2[((size_t)0 * N + dl) * H_HEADS + head];
        float sc1 = s1[((size_t)1 * N + n) * H_HEADS + head] +
                    s2[((size_t)1 * N + dl) * H_HEADS + head];
        sc0 = sc0 >= 0.f ? sc0 : 0.2f * sc0;
        sc1 = sc1 >= 0.f ? sc1 : 0.2f * sc1;
        float m = fmaxf(sc0, sc1);
        float e0 = __expf(sc0 - m), e1 = __expf(sc1 - m);
        wgt = (b == 0 ? e0 : e1) / (e0 + e1);
    }

    float acc[8] = {};
    const u16* hb = h + (size_t)b * N * FOUT + lane * 8;
    for (int j0 = 0; j0 < deg; j0 += 4) {
#pragma unroll
        for (int k = 0; k < 4; k++) {
            int j = j0 + k;
            float f = (j < deg) ? 1.0f : 0.0f;     // wave-uniform
            int dn = (j < deg) ? __shfl(myidx, j) : 0;
            uint4 v = *(const uint4*)(hb + (size_t)dn * FOUT);
            acc[0] = fmaf(f, bf2f(v.x & 0xffffu), acc[0]);
            acc[1] = fmaf(f, bf2f(v.x >> 16), acc[1]);
            acc[2] = fmaf(f, bf2f(v.y & 0xffffu), acc[2]);
            acc[3] = fmaf(f, bf2f(v.y >> 16), acc[3]);
            acc[4] = fmaf(f, bf2f(v.z & 0xffffu), acc[4]);
            acc[5] = fmaf(f, bf2f(v.z >> 16), acc[5]);
            acc[6] = fmaf(f, bf2f(v.w & 0xffffu), acc[6]);
            acc[7] = fmaf(f, bf2f(v.w >> 16), acc[7]);
        }
    }

    float val[8];
#pragma unroll
    for (int k = 0; k < 8; k++) val[k] = acc[k] * wgt;
#pragma unroll
    for (int m = 8; m <= 32; m <<= 1)
#pragma unroll
        for (int k = 0; k < 8; k++) val[k] += __shfl_xor(val[k], m);
    if (lane < 8) {
        float* op = out + ((size_t)b * N + n) * DDIM + lane * 8;
        const float inv = 1.0f / H_HEADS;
        *(float4*)op = make_float4(val[0] * inv, val[1] * inv, val[2] * inv,
                                   val[3] * inv);
        *(float4*)(op + 4) = make_float4(val[4] * inv, val[5] * inv,
                                         val[6] * inv, val[7] * inv);
    }
}

// ---------------------------------------------------------------------------
extern "C" void kernel_launch(void* const* d_in, const int* in_sizes, int n_in,
                              void* d_out, int out_size, void* d_ws,
                              size_t ws_size, hipStream_t stream) {
    const float* x = (const float*)d_in[0];
    const int* edges = (const int*)d_in[1];
    const float* W = (const float*)d_in[2];
    const float* a = (const float*)d_in[3];
    float* out = (float*)d_out;

    const int* src = edges;
    const int* dst = edges + EDGES;

    char* p = (char*)d_ws;
    auto carve = [&](size_t bytes) {
        char* r = p;
        p += (bytes + 255) & ~(size_t)255;
        return r;
    };
    u16* Wb = (u16*)carve((size_t)FOUT * FIN * 2);
    u16* h = (u16*)carve((size_t)BB * NNODES * FOUT * 2);
    float* s1 = (float*)carve((size_t)BB * NNODES * H_HEADS * 4);
    float* s2 = (float*)carve((size_t)BB * NNODES * H_HEADS * 4);
    int* cursor = (int*)carve(NNODES * 4);       // adjacent to le_pack:
    int* le_pack = (int*)carve(NNODES * 4);      // 32768B carve = 256-mult
    int* csr_dst = (int*)carve((size_t)NNODES * CAP * 4);

    const int M = BB * NNODES;

    // 3 dispatches (was memset+prep+gemm+agg = 4); K1 zeroes cursor+le_pack
    // (carve-adjacent) and casts W; K2 folds the edge build under the gemm.
    init_kernel<<<128, 256, 0, stream>>>(W, Wb, cursor);
    gemm_edges<<<(M / 128) * (FOUT / 128), 256, 0, stream>>>(
        x, Wb, a, src, dst, h, s1, s2, cursor, le_pack, csr_dst);
    aggregate<<<NNODES / 2, 256, 0, stream>>>(h, s1, s2, cursor, le_pack,
                                              csr_dst, out, NNODES);
}